// Round 5
// baseline (7010.815 us; speedup 1.0000x reference)
//
#include <hip/hip_runtime.h>
#include <hip/hip_bf16.h>

// Problem: 2-layer LSTM (T=1024, B=512, IN=20, H1=128, H2=64) + head OUT=3.
// KEY: reference takes h2[:, -1, :] => only batch element 511 matters.
//
// Round-5: R3/R4 both failed weight-VGPR residency because demand sat just
// over the occupancy-forced register cap (R4: 142 > 128 @ 16 waves), so the
// allocator rematerialized weight loads into the loop (~448KB/step from L2).
// Fix: (a) shrink per-thread resident weights to 80 f32 (W_hh0 64 + W_hh1 16),
// W_ih1 lives in LDS (128KB, padded rows); (b) pin the 20 weight quads with an
// opaque `asm volatile("" : "+v"(..))` so re-loading from global is illegal.

#define T_STEPS 1024
#define BATCH   512
#define IN_F    20
#define H1_     128
#define H2_     64
#define OUT_F   3
#define G1_     (4*H1_)   // 512 layer-1 gates
#define G2_     (4*H2_)   // 256 layer-2 gates

typedef float f4 __attribute__((ext_vector_type(4)));
typedef float f2 __attribute__((ext_vector_type(2)));

__device__ __forceinline__ float sigmoidf_(float x) {
    return 1.0f / (1.0f + __expf(-x));
}
// tanh(x) = 1 - 2/(exp(2x)+1); stable at +-inf via exp overflow/underflow
__device__ __forceinline__ float tanhf_(float x) {
    return 1.0f - 2.0f / (__expf(2.0f * x) + 1.0f);
}

#define REP4(M)  M(0) M(1) M(2) M(3)
#define REP8(M)  REP4(M) M(4) M(5) M(6) M(7)

// ---------------- Kernel A: x-projection for batch row 511 -------------------
__global__ void xproj_kernel(const float* __restrict__ x,
                             const float* __restrict__ W_ih0,
                             const float* __restrict__ b_ih0,
                             const float* __restrict__ b_hh0,
                             float* __restrict__ xp1)
{
    const int t = blockIdx.x;
    const int g = threadIdx.x;
    const float* xr = x + ((size_t)t * BATCH + (BATCH - 1)) * IN_F;
    const float* w  = W_ih0 + g * IN_F;
    float acc = b_ih0[g] + b_hh0[g];
#pragma unroll
    for (int i = 0; i < IN_F; ++i) acc = fmaf(xr[i], w[i], acc);
    xp1[t * G1_ + g] = acc;
}

// ---------------- Kernel B: sequential 2-layer LSTM scan, 1 block ------------
// 1024 threads (16 waves, 4/SIMD, 128-VGPR tier). cb = tid>>8 (0..3), rp = tid&255.
//   L1: thread owns gate-rows {2rp,2rp+1}, cols [32cb,32cb+32)  -> 64 regs (pinned)
//   L2: thread owns gate rp; W_hh1[rp][16cb..16cb+16) -> 16 regs (pinned);
//       W_ih1[rp][32cb..32cb+32) read from LDS each step (padded stride 33 quads).
// Partials combined via padded LDS buffers (stride 5). 3 barriers/step.
__global__ __attribute__((amdgpu_flat_work_group_size(1024, 1024)))
void lstm_seq_kernel(const float* __restrict__ xp1,
                     const float* __restrict__ W_hh0,
                     const float* __restrict__ W_ih1,
                     const float* __restrict__ W_hh1,
                     const float* __restrict__ b_ih1,
                     const float* __restrict__ b_hh1,
                     float* __restrict__ h2seq)
{
    const int tid = threadIdx.x;
    const int cb  = tid >> 8;      // wave-uniform quarter
    const int rp  = tid & 255;

    __shared__ f4    sc[48];            // [0..31]=h1 (128 f32), [32..47]=h2 (64)
    __shared__ float sp1[G1_ * 5];      // L1 partials, padded stride 5 (10 KB)
    __shared__ float sp2[G2_ * 5];      // L2 partials + bias in slot 4 (5 KB)
    __shared__ f4    swih1[256 * 33];   // W_ih1, rows padded 32->33 quads (135 KB)

    // ---- stage W_ih1 into LDS (once) ---------------------------------------
    for (int i = tid; i < 256 * 32; i += 1024) {
        const int row = i >> 5, col = i & 31;
        swih1[row * 33 + col] = ((const f4*)W_ih1)[row * 32 + col];
    }

    // ---- register-resident weights (pinned) --------------------------------
    const f4* pr0 = (const f4*)(W_hh0 + (size_t)(2 * rp)     * H1_ + 32 * cb);
    const f4* pr1 = (const f4*)(W_hh0 + (size_t)(2 * rp + 1) * H1_ + 32 * cb);
#define DWA(k) f4 w0_##k = pr0[k]; f4 w1_##k = pr1[k];
    REP8(DWA)
#undef DWA
    const f4* ph = (const f4*)(W_hh1 + (size_t)rp * H2_ + 16 * cb);
    f4 wh0 = ph[0], wh1 = ph[1], wh2 = ph[2], wh3 = ph[3];

    // Opaque pin: values may have been modified -> compiler cannot re-load
    // them from global inside the loop; must keep in VGPRs (demand ~110 < 128).
    asm volatile("" : "+v"(w0_0), "+v"(w0_1), "+v"(w0_2), "+v"(w0_3),
                      "+v"(w0_4), "+v"(w0_5), "+v"(w0_6), "+v"(w0_7),
                      "+v"(w1_0), "+v"(w1_1), "+v"(w1_2), "+v"(w1_3),
                      "+v"(w1_4), "+v"(w1_5), "+v"(w1_6), "+v"(w1_7),
                      "+v"(wh0), "+v"(wh1), "+v"(wh2), "+v"(wh3));

    // ---- init: zero state, stage L2 biases into sp2 pad slot ---------------
    if (tid < 48) sc[tid] = f4{0.f, 0.f, 0.f, 0.f};
    if (tid < G2_) sp2[tid * 5 + 4] = b_ih1[tid] + b_hh1[tid];
    float c1 = 0.0f;   // owned by tid < 128
    float c2 = 0.0f;   // owned by tid < 64
    __syncthreads();

    const f4* scp1  = sc + 8 * cb;             // h1 slice for P1 (broadcast)
    const f4* scp3a = sc + 8 * cb;             // h1 slice for P3 (broadcast)
    const f4* scp3b = sc + 32 + 4 * cb;        // h2 slice for P3 (broadcast)
    const f4* wrow  = swih1 + rp * 33 + 8 * cb; // LDS W_ih1 slice

    for (int t = 0; t < T_STEPS; ++t) {
        // ---- P1: L1 partials; cb==0 threads add xp (2 gates, 8B load) ------
        f2 xpv = f2{0.f, 0.f};
        if (cb == 0) xpv = *(const f2*)(xp1 + (size_t)t * G1_ + 2 * rp);

        float a0x = 0.f, a0y = 0.f, a0z = 0.f, a0w = 0.f;
        float a1x = 0.f, a1y = 0.f, a1z = 0.f, a1w = 0.f;
#define P1S(k) { const f4 h4 = scp1[k];                                      \
        a0x = fmaf(w0_##k.x, h4.x, a0x); a0y = fmaf(w0_##k.y, h4.y, a0y);    \
        a0z = fmaf(w0_##k.z, h4.z, a0z); a0w = fmaf(w0_##k.w, h4.w, a0w);    \
        a1x = fmaf(w1_##k.x, h4.x, a1x); a1y = fmaf(w1_##k.y, h4.y, a1y);    \
        a1z = fmaf(w1_##k.z, h4.z, a1z); a1w = fmaf(w1_##k.w, h4.w, a1w); }
        REP8(P1S)
#undef P1S
        sp1[(2 * rp)     * 5 + cb] = ((a0x + a0y) + (a0z + a0w)) + xpv.x;
        sp1[(2 * rp + 1) * 5 + cb] = ((a1x + a1y) + (a1z + a1w)) + xpv.y;
        __syncthreads();   // B1: sp1 ready (also orders prev P4's h2 writes)

        // ---- P2 (tid<128): combine 4 partials/gate, activate, h1_new -------
        if (tid < H1_) {
            const float* s = sp1 + tid * 5;
            const float vi = (s[0]    + s[1])    + (s[2]    + s[3]);
            const float vf = (s[640]  + s[641])  + (s[642]  + s[643]);
            const float vg = (s[1280] + s[1281]) + (s[1282] + s[1283]);
            const float vo = (s[1920] + s[1921]) + (s[1922] + s[1923]);
            c1 = fmaf(sigmoidf_(vf), c1, sigmoidf_(vi) * tanhf_(vg));
            const float h = sigmoidf_(vo) * tanhf_(c1);
            ((float*)sc)[tid] = h;
        }
        __syncthreads();   // B2: h1_new ready

        // ---- P3: L2 partials: LDS W_ih1 . h1_new  +  reg W_hh1 . h2_old ----
        {
            float bx = 0.f, by = 0.f, bz = 0.f, bw = 0.f;
#define P3S(k) { const f4 h4 = scp3a[k]; const f4 w4 = wrow[k];              \
            bx = fmaf(w4.x, h4.x, bx); by = fmaf(w4.y, h4.y, by);            \
            bz = fmaf(w4.z, h4.z, bz); bw = fmaf(w4.w, h4.w, bw); }
            REP8(P3S)
#undef P3S
            {
                const f4 h0 = scp3b[0], h1v = scp3b[1], h2v = scp3b[2], h3v = scp3b[3];
                bx = fmaf(wh0.x, h0.x, bx); by = fmaf(wh0.y, h0.y, by);
                bz = fmaf(wh0.z, h0.z, bz); bw = fmaf(wh0.w, h0.w, bw);
                bx = fmaf(wh1.x, h1v.x, bx); by = fmaf(wh1.y, h1v.y, by);
                bz = fmaf(wh1.z, h1v.z, bz); bw = fmaf(wh1.w, h1v.w, bw);
                bx = fmaf(wh2.x, h2v.x, bx); by = fmaf(wh2.y, h2v.y, by);
                bz = fmaf(wh2.z, h2v.z, bz); bw = fmaf(wh2.w, h2v.w, bw);
                bx = fmaf(wh3.x, h3v.x, bx); by = fmaf(wh3.y, h3v.y, by);
                bz = fmaf(wh3.z, h3v.z, bz); bw = fmaf(wh3.w, h3v.w, bw);
            }
            sp2[rp * 5 + cb] = (bx + by) + (bz + bw);
        }
        __syncthreads();   // B3: sp2 ready

        // ---- P4 (tid<64): combine, activate, h2_new, store -----------------
        // No trailing barrier: next P1 touches only sc[0..31]/sp1/xp; B1 of
        // step t+1 orders these h2 writes before next P3 reads.
        if (tid < H2_) {
            const float* s = sp2 + tid * 5;
            const float vi = ((s[0]   + s[1])   + (s[2]   + s[3]))   + s[4];
            const float vf = ((s[320] + s[321]) + (s[322] + s[323])) + s[324];
            const float vg = ((s[640] + s[641]) + (s[642] + s[643])) + s[644];
            const float vo = ((s[960] + s[961]) + (s[962] + s[963])) + s[964];
            c2 = fmaf(sigmoidf_(vf), c2, sigmoidf_(vi) * tanhf_(vg));
            const float h = sigmoidf_(vo) * tanhf_(c2);
            ((float*)sc)[H1_ + tid] = h;
            h2seq[(size_t)t * H2_ + tid] = h;
        }
    }
}

// ---------------- Kernel C: output head out[t,o] = relu(h2[t]) . W_d[o] + b_d
__global__ void head_kernel(const float* __restrict__ h2seq,
                            const float* __restrict__ W_d,
                            const float* __restrict__ b_d,
                            float* __restrict__ out)
{
    const int idx = blockIdx.x * blockDim.x + threadIdx.x;
    if (idx >= T_STEPS * OUT_F) return;
    const int t = idx / OUT_F;
    const int o = idx - t * OUT_F;
    const float* hr = h2seq + t * H2_;
    const float* w  = W_d + o * H2_;
    float acc = b_d[o];
#pragma unroll
    for (int j = 0; j < H2_; ++j) acc = fmaf(fmaxf(hr[j], 0.0f), w[j], acc);
    out[idx] = acc;
}

extern "C" void kernel_launch(void* const* d_in, const int* in_sizes, int n_in,
                              void* d_out, int out_size, void* d_ws, size_t ws_size,
                              hipStream_t stream) {
    const float* x     = (const float*)d_in[0];
    const float* W_ih0 = (const float*)d_in[1];
    const float* W_hh0 = (const float*)d_in[2];
    const float* b_ih0 = (const float*)d_in[3];
    const float* b_hh0 = (const float*)d_in[4];
    const float* W_ih1 = (const float*)d_in[5];
    const float* W_hh1 = (const float*)d_in[6];
    const float* b_ih1 = (const float*)d_in[7];
    const float* b_hh1 = (const float*)d_in[8];
    const float* W_d   = (const float*)d_in[9];
    const float* b_d   = (const float*)d_in[10];

    float* out   = (float*)d_out;
    float* xp1   = (float*)d_ws;                // [1024][512] f32 = 2 MB
    float* h2seq = xp1 + (size_t)T_STEPS * G1_; // [1024][64]  f32 = 256 KB

    hipLaunchKernelGGL(xproj_kernel, dim3(T_STEPS), dim3(G1_), 0, stream,
                       x, W_ih0, b_ih0, b_hh0, xp1);
    hipLaunchKernelGGL(lstm_seq_kernel, dim3(1), dim3(1024), 0, stream,
                       xp1, W_hh0, W_ih1, W_hh1, b_ih1, b_hh1, h2seq);
    hipLaunchKernelGGL(head_kernel, dim3((T_STEPS * OUT_F + 255) / 256), dim3(256),
                       0, stream, h2seq, W_d, b_d, out);
}

// Round 6
// 1590.165 us; speedup vs baseline: 4.4089x; 4.4089x over previous
//
#include <hip/hip_runtime.h>
#include <hip/hip_bf16.h>

// 2-layer LSTM (T=1024, B=512, IN=20, H1=128, H2=64) + head OUT=3.
// Only batch row 511 feeds the output => single-sequence scan.
//
// Round-6 restructure: only W_hh*h is truly sequential. Pipeline:
//   A : xp1 = x[:,511,:] @ W_ih0^T + b0            (parallel)
//   B1: layer-1 scan, per-thread 64 weight regs    (serial, 1 CU)
//   C1: xp2 = h1seq @ W_ih1^T + b1                 (parallel GEMM)
//   B2: layer-2 scan, per-thread 32 weight regs    (serial, 1 CU)
//   D : head                                        (parallel)
// This removes W_ih1 (2/3 of serial FLOPs) from the scan entirely and cuts
// per-thread register demand to 64/32 f32 — far under the remat threshold
// that defeated rounds 3-5.

#define T_STEPS 1024
#define BATCH   512
#define IN_F    20
#define H1_     128
#define H2_     64
#define OUT_F   3
#define G1_     (4*H1_)   // 512
#define G2_     (4*H2_)   // 256

typedef float f4 __attribute__((ext_vector_type(4)));

__device__ __forceinline__ float sigmoidf_(float x) {
    return 1.0f / (1.0f + __expf(-x));
}
__device__ __forceinline__ float tanhf_(float x) {
    return 1.0f - 2.0f / (__expf(2.0f * x) + 1.0f);
}

#define REP8(M)  M(0) M(1) M(2) M(3) M(4) M(5) M(6) M(7)
#define REP16(M) REP8(M) M(8) M(9) M(10) M(11) M(12) M(13) M(14) M(15)

// ---------------- A: x-projection for batch row 511 --------------------------
__global__ void xproj_kernel(const float* __restrict__ x,
                             const float* __restrict__ W_ih0,
                             const float* __restrict__ b_ih0,
                             const float* __restrict__ b_hh0,
                             float* __restrict__ xp1)
{
    const int t = blockIdx.x;
    const int g = threadIdx.x;
    const float* xr = x + ((size_t)t * BATCH + (BATCH - 1)) * IN_F;
    const float* w  = W_ih0 + g * IN_F;
    float acc = b_ih0[g] + b_hh0[g];
#pragma unroll
    for (int i = 0; i < IN_F; ++i) acc = fmaf(xr[i], w[i], acc);
    xp1[t * G1_ + g] = acc;
}

// ---------------- B1: layer-1 scan (serial, one block) -----------------------
// 1024 threads. g = tid&511 (gate), hf = tid>>9 (column half, wave-uniform).
// Weights: W_hh0[g][hf*64 .. hf*64+64) = 16 f4 in registers.
// Partials: sp1[g*3+hf] (stride 3 => conflict-free). 2 barriers/step.
__global__ __attribute__((amdgpu_flat_work_group_size(1024, 1024)))
void lstm1_kernel(const float* __restrict__ xp1,
                  const float* __restrict__ W_hh0,
                  float* __restrict__ h1seq)
{
    const int tid = threadIdx.x;
    const int g   = tid & 511;
    const int hf  = tid >> 9;          // wave-uniform

    __shared__ f4    sh1[H1_ / 4];     // h1 state (128 f32)
    __shared__ float sp1[G1_ * 3];     // partials, stride 3 (6 KB)

    const f4* pw = (const f4*)(W_hh0 + (size_t)g * H1_ + hf * 64);
#define DW(k) f4 w_##k = pw[k];
    REP16(DW)
#undef DW
    // opaque pin: compiler may not re-derive these from memory in the loop
    asm volatile("" : "+v"(w_0), "+v"(w_1), "+v"(w_2), "+v"(w_3),
                      "+v"(w_4), "+v"(w_5), "+v"(w_6), "+v"(w_7),
                      "+v"(w_8), "+v"(w_9), "+v"(w_10), "+v"(w_11),
                      "+v"(w_12), "+v"(w_13), "+v"(w_14), "+v"(w_15));

    if (tid < H1_ / 4) sh1[tid] = f4{0.f, 0.f, 0.f, 0.f};
    float c1 = 0.0f;                   // owned by tid < 128
    __syncthreads();

    const f4* hb = sh1 + hf * 16;
    float xp_cur = (hf == 0) ? xp1[g] : 0.0f;

    for (int t = 0; t < T_STEPS; ++t) {
        // prefetch next step's xp (hidden by this step's compute)
        float xp_next = 0.0f;
        {
            const int tn = (t + 1 < T_STEPS) ? (t + 1) : (T_STEPS - 1);
            if (hf == 0) xp_next = xp1[(size_t)tn * G1_ + g];
        }

        float ax = 0.f, ay = 0.f, az = 0.f, aw = 0.f;
#define P1S(k) { const f4 h4 = hb[k];                                        \
        ax = fmaf(w_##k.x, h4.x, ax); ay = fmaf(w_##k.y, h4.y, ay);          \
        az = fmaf(w_##k.z, h4.z, az); aw = fmaf(w_##k.w, h4.w, aw); }
        REP16(P1S)
#undef P1S
        sp1[g * 3 + hf] = ((ax + ay) + (az + aw)) + xp_cur;
        __syncthreads();   // B1: sp1 ready (also orders prev h1 writes)

        if (tid < H1_) {
            const float vi = sp1[tid * 3]         + sp1[tid * 3 + 1];
            const float vf = sp1[(H1_   + tid)*3] + sp1[(H1_   + tid)*3 + 1];
            const float vg = sp1[(2*H1_ + tid)*3] + sp1[(2*H1_ + tid)*3 + 1];
            const float vo = sp1[(3*H1_ + tid)*3] + sp1[(3*H1_ + tid)*3 + 1];
            c1 = fmaf(sigmoidf_(vf), c1, sigmoidf_(vi) * tanhf_(vg));
            const float h = sigmoidf_(vo) * tanhf_(c1);
            ((float*)sh1)[tid] = h;
            h1seq[(size_t)t * H1_ + tid] = h;   // fire-and-forget
        }
        __syncthreads();   // B2: h1_new ready
        xp_cur = xp_next;
    }
}

// ---------------- C1: xp2 = h1seq @ W_ih1^T + (b_ih1 + b_hh1) ---------------
// 1024 blocks (one per t) x 256 threads (one per gate).
__global__ void xproj2_kernel(const float* __restrict__ h1seq,
                              const float* __restrict__ W_ih1,
                              const float* __restrict__ b_ih1,
                              const float* __restrict__ b_hh1,
                              float* __restrict__ xp2)
{
    const int t = blockIdx.x;
    const int g = threadIdx.x;
    __shared__ f4 sh[H1_ / 4];
    if (g < H1_ / 4) sh[g] = ((const f4*)(h1seq + (size_t)t * H1_))[g];
    __syncthreads();
    const f4* w = (const f4*)(W_ih1 + (size_t)g * H1_);
    float ax = 0.f, ay = 0.f, az = 0.f, aw = 0.f;
#pragma unroll
    for (int k = 0; k < H1_ / 4; ++k) {
        const f4 h4 = sh[k]; const f4 w4 = w[k];
        ax = fmaf(w4.x, h4.x, ax); ay = fmaf(w4.y, h4.y, ay);
        az = fmaf(w4.z, h4.z, az); aw = fmaf(w4.w, h4.w, aw);
    }
    xp2[(size_t)t * G2_ + g] = ((ax + ay) + (az + aw)) + b_ih1[g] + b_hh1[g];
}

// ---------------- B2: layer-2 scan (serial, one block) -----------------------
// 512 threads. g = tid&255 (gate), hf = tid>>8 (column half, wave-uniform).
// Weights: W_hh1[g][hf*32 .. hf*32+32) = 8 f4 in registers.
__global__ __attribute__((amdgpu_flat_work_group_size(512, 512)))
void lstm2_kernel(const float* __restrict__ xp2,
                  const float* __restrict__ W_hh1,
                  float* __restrict__ h2seq)
{
    const int tid = threadIdx.x;
    const int g   = tid & 255;
    const int hf  = tid >> 8;          // wave-uniform

    __shared__ f4    sh2[H2_ / 4];     // h2 state (64 f32)
    __shared__ float sp2[G2_ * 3];     // partials, stride 3 (3 KB)

    const f4* pw = (const f4*)(W_hh1 + (size_t)g * H2_ + hf * 32);
#define DW(k) f4 w_##k = pw[k];
    REP8(DW)
#undef DW
    asm volatile("" : "+v"(w_0), "+v"(w_1), "+v"(w_2), "+v"(w_3),
                      "+v"(w_4), "+v"(w_5), "+v"(w_6), "+v"(w_7));

    if (tid < H2_ / 4) sh2[tid] = f4{0.f, 0.f, 0.f, 0.f};
    float c2 = 0.0f;                   // owned by tid < 64
    __syncthreads();

    const f4* hb = sh2 + hf * 8;
    float xp_cur = (hf == 0) ? xp2[g] : 0.0f;

    for (int t = 0; t < T_STEPS; ++t) {
        float xp_next = 0.0f;
        {
            const int tn = (t + 1 < T_STEPS) ? (t + 1) : (T_STEPS - 1);
            if (hf == 0) xp_next = xp2[(size_t)tn * G2_ + g];
        }

        float ax = 0.f, ay = 0.f, az = 0.f, aw = 0.f;
#define P1S(k) { const f4 h4 = hb[k];                                        \
        ax = fmaf(w_##k.x, h4.x, ax); ay = fmaf(w_##k.y, h4.y, ay);          \
        az = fmaf(w_##k.z, h4.z, az); aw = fmaf(w_##k.w, h4.w, aw); }
        REP8(P1S)
#undef P1S
        sp2[g * 3 + hf] = ((ax + ay) + (az + aw)) + xp_cur;
        __syncthreads();   // sp2 ready

        if (tid < H2_) {
            const float vi = sp2[tid * 3]         + sp2[tid * 3 + 1];
            const float vf = sp2[(H2_   + tid)*3] + sp2[(H2_   + tid)*3 + 1];
            const float vg = sp2[(2*H2_ + tid)*3] + sp2[(2*H2_ + tid)*3 + 1];
            const float vo = sp2[(3*H2_ + tid)*3] + sp2[(3*H2_ + tid)*3 + 1];
            c2 = fmaf(sigmoidf_(vf), c2, sigmoidf_(vi) * tanhf_(vg));
            const float h = sigmoidf_(vo) * tanhf_(c2);
            ((float*)sh2)[tid] = h;
            h2seq[(size_t)t * H2_ + tid] = h;
        }
        __syncthreads();   // h2_new ready
        xp_cur = xp_next;
    }
}

// ---------------- D: head out[t,o] = relu(h2[t]) . W_d[o] + b_d --------------
__global__ void head_kernel(const float* __restrict__ h2seq,
                            const float* __restrict__ W_d,
                            const float* __restrict__ b_d,
                            float* __restrict__ out)
{
    const int idx = blockIdx.x * blockDim.x + threadIdx.x;
    if (idx >= T_STEPS * OUT_F) return;
    const int t = idx / OUT_F;
    const int o = idx - t * OUT_F;
    const float* hr = h2seq + (size_t)t * H2_;
    const float* w  = W_d + o * H2_;
    float acc = b_d[o];
#pragma unroll
    for (int j = 0; j < H2_; ++j) acc = fmaf(fmaxf(hr[j], 0.0f), w[j], acc);
    out[idx] = acc;
}

extern "C" void kernel_launch(void* const* d_in, const int* in_sizes, int n_in,
                              void* d_out, int out_size, void* d_ws, size_t ws_size,
                              hipStream_t stream) {
    const float* x     = (const float*)d_in[0];
    const float* W_ih0 = (const float*)d_in[1];
    const float* W_hh0 = (const float*)d_in[2];
    const float* b_ih0 = (const float*)d_in[3];
    const float* b_hh0 = (const float*)d_in[4];
    const float* W_ih1 = (const float*)d_in[5];
    const float* W_hh1 = (const float*)d_in[6];
    const float* b_ih1 = (const float*)d_in[7];
    const float* b_hh1 = (const float*)d_in[8];
    const float* W_d   = (const float*)d_in[9];
    const float* b_d   = (const float*)d_in[10];

    float* out   = (float*)d_out;
    float* xp1   = (float*)d_ws;                       // [1024][512] = 2 MB
    float* h1seq = xp1 + (size_t)T_STEPS * G1_;        // [1024][128] = 512 KB
    float* h2seq = h1seq + (size_t)T_STEPS * H1_;      // [1024][64]  = 256 KB
    float* xp2   = xp1;                                // overlay (xp1 dead after B1)

    hipLaunchKernelGGL(xproj_kernel, dim3(T_STEPS), dim3(G1_), 0, stream,
                       x, W_ih0, b_ih0, b_hh0, xp1);
    hipLaunchKernelGGL(lstm1_kernel, dim3(1), dim3(1024), 0, stream,
                       xp1, W_hh0, h1seq);
    hipLaunchKernelGGL(xproj2_kernel, dim3(T_STEPS), dim3(G2_), 0, stream,
                       h1seq, W_ih1, b_ih1, b_hh1, xp2);
    hipLaunchKernelGGL(lstm2_kernel, dim3(1), dim3(512), 0, stream,
                       xp2, W_hh1, h2seq);
    hipLaunchKernelGGL(head_kernel, dim3((T_STEPS * OUT_F + 255) / 256), dim3(256),
                       0, stream, h2seq, W_d, b_d, out);
}

// Round 7
// 1580.644 us; speedup vs baseline: 4.4354x; 1.0060x over previous
//
#include <hip/hip_runtime.h>
#include <hip/hip_bf16.h>

// 2-layer LSTM (T=1024, B=512, IN=20, H1=128, H2=64) + head OUT=3.
// Only batch row 511 feeds the output => single-sequence scan.
//
// Pipeline:
//   A : xp1 = x[:,511,:] @ W_ih0^T + b0            (parallel)
//   B1: layer-1 scan                                (serial, 1 CU)
//   C1: xp2 = h1seq @ W_ih1^T + b1                 (parallel GEMM)
//   B2: layer-2 scan                                (serial, 1 CU)
//   D : head                                        (parallel)
//
// Round-7: R2-R6 showed plain loads of loop-invariant weights ALWAYS get
// rematerialized into the scan loop by the RA (invariant+dereferenceable =>
// re-load instead of keep-live; ~256KB/step from L2 = 1.0us/step). Fix: load
// weights via inline-asm global_load_dwordx4 — asm results cannot be remat'd,
// and with demand ~90 regs under the waves_per_eu(4,4) budget (128) they
// won't spill either.

#define T_STEPS 1024
#define BATCH   512
#define IN_F    20
#define H1_     128
#define H2_     64
#define OUT_F   3
#define G1_     (4*H1_)   // 512
#define G2_     (4*H2_)   // 256

typedef float f4 __attribute__((ext_vector_type(4)));

__device__ __forceinline__ float sigmoidf_(float x) {
    return 1.0f / (1.0f + __expf(-x));
}
__device__ __forceinline__ float tanhf_(float x) {
    return 1.0f - 2.0f / (__expf(2.0f * x) + 1.0f);
}

#define REP16(M) M(0) M(1) M(2) M(3) M(4) M(5) M(6) M(7) \
                 M(8) M(9) M(10) M(11) M(12) M(13) M(14) M(15)

// Load 16 consecutive float4 (256B) into named regs via inline asm.
// Inline-asm outputs are not rematerializable => weights stay VGPR-resident.
#define ASM_LOAD_16Q(PTR)                                                     \
    asm volatile(                                                             \
        "global_load_dwordx4 %0,  %16, off\n\t"                              \
        "global_load_dwordx4 %1,  %16, off offset:16\n\t"                    \
        "global_load_dwordx4 %2,  %16, off offset:32\n\t"                    \
        "global_load_dwordx4 %3,  %16, off offset:48\n\t"                    \
        "global_load_dwordx4 %4,  %16, off offset:64\n\t"                    \
        "global_load_dwordx4 %5,  %16, off offset:80\n\t"                    \
        "global_load_dwordx4 %6,  %16, off offset:96\n\t"                    \
        "global_load_dwordx4 %7,  %16, off offset:112\n\t"                   \
        "global_load_dwordx4 %8,  %16, off offset:128\n\t"                   \
        "global_load_dwordx4 %9,  %16, off offset:144\n\t"                   \
        "global_load_dwordx4 %10, %16, off offset:160\n\t"                   \
        "global_load_dwordx4 %11, %16, off offset:176\n\t"                   \
        "global_load_dwordx4 %12, %16, off offset:192\n\t"                   \
        "global_load_dwordx4 %13, %16, off offset:208\n\t"                   \
        "global_load_dwordx4 %14, %16, off offset:224\n\t"                   \
        "global_load_dwordx4 %15, %16, off offset:240\n\t"                   \
        "s_waitcnt vmcnt(0)"                                                  \
        : "=&v"(w_0), "=&v"(w_1), "=&v"(w_2), "=&v"(w_3),                    \
          "=&v"(w_4), "=&v"(w_5), "=&v"(w_6), "=&v"(w_7),                    \
          "=&v"(w_8), "=&v"(w_9), "=&v"(w_10), "=&v"(w_11),                  \
          "=&v"(w_12), "=&v"(w_13), "=&v"(w_14), "=&v"(w_15)                 \
        : "v"(PTR))

// ---------------- A: x-projection for batch row 511 --------------------------
__global__ void xproj_kernel(const float* __restrict__ x,
                             const float* __restrict__ W_ih0,
                             const float* __restrict__ b_ih0,
                             const float* __restrict__ b_hh0,
                             float* __restrict__ xp1)
{
    const int t = blockIdx.x;
    const int g = threadIdx.x;
    const float* xr = x + ((size_t)t * BATCH + (BATCH - 1)) * IN_F;
    const float* w  = W_ih0 + g * IN_F;
    float acc = b_ih0[g] + b_hh0[g];
#pragma unroll
    for (int i = 0; i < IN_F; ++i) acc = fmaf(xr[i], w[i], acc);
    xp1[t * G1_ + g] = acc;
}

// ---------------- B1: layer-1 scan (serial, one block) -----------------------
// 1024 threads. g = tid&511 (gate), hf = tid>>9 (column half, wave-uniform).
// Weights: W_hh0[g][hf*64 .. hf*64+64) = 16 f4 in VGPRs (asm-loaded).
// Partials: sp1[g*3+hf] (stride 3 => conflict-free). 2 barriers/step.
__global__ __attribute__((amdgpu_flat_work_group_size(1024, 1024),
                          amdgpu_waves_per_eu(4, 4)))
void lstm1_kernel(const float* __restrict__ xp1,
                  const float* __restrict__ W_hh0,
                  float* __restrict__ h1seq)
{
    const int tid = threadIdx.x;
    const int g   = tid & 511;
    const int hf  = tid >> 9;          // wave-uniform

    __shared__ f4    sh1[H1_ / 4];     // h1 state (128 f32)
    __shared__ float sp1[G1_ * 3];     // partials, stride 3 (6 KB)

    const f4* pw = (const f4*)(W_hh0 + (size_t)g * H1_ + hf * 64);
    f4 w_0, w_1, w_2, w_3, w_4, w_5, w_6, w_7,
       w_8, w_9, w_10, w_11, w_12, w_13, w_14, w_15;
    ASM_LOAD_16Q(pw);

    if (tid < H1_ / 4) sh1[tid] = f4{0.f, 0.f, 0.f, 0.f};
    float c1 = 0.0f;                   // owned by tid < 128
    __syncthreads();

    const f4* hb = sh1 + hf * 16;
    float xp_cur = (hf == 0) ? xp1[g] : 0.0f;

    for (int t = 0; t < T_STEPS; ++t) {
        float xp_next = 0.0f;
        {
            const int tn = (t + 1 < T_STEPS) ? (t + 1) : (T_STEPS - 1);
            if (hf == 0) xp_next = xp1[(size_t)tn * G1_ + g];
        }

        float ax = 0.f, ay = 0.f, az = 0.f, aw = 0.f;
#define P1S(k) { const f4 h4 = hb[k];                                        \
        ax = fmaf(w_##k.x, h4.x, ax); ay = fmaf(w_##k.y, h4.y, ay);          \
        az = fmaf(w_##k.z, h4.z, az); aw = fmaf(w_##k.w, h4.w, aw); }
        REP16(P1S)
#undef P1S
        sp1[g * 3 + hf] = ((ax + ay) + (az + aw)) + xp_cur;
        __syncthreads();   // sp1 ready (also orders prev h1 writes)

        if (tid < H1_) {
            const float vi = sp1[tid * 3]         + sp1[tid * 3 + 1];
            const float vf = sp1[(H1_   + tid)*3] + sp1[(H1_   + tid)*3 + 1];
            const float vg = sp1[(2*H1_ + tid)*3] + sp1[(2*H1_ + tid)*3 + 1];
            const float vo = sp1[(3*H1_ + tid)*3] + sp1[(3*H1_ + tid)*3 + 1];
            c1 = fmaf(sigmoidf_(vf), c1, sigmoidf_(vi) * tanhf_(vg));
            const float h = sigmoidf_(vo) * tanhf_(c1);
            ((float*)sh1)[tid] = h;
            h1seq[(size_t)t * H1_ + tid] = h;   // fire-and-forget
        }
        __syncthreads();   // h1_new ready
        xp_cur = xp_next;
    }
}

// ---------------- C1: xp2 = h1seq @ W_ih1^T + (b_ih1 + b_hh1) ---------------
__global__ void xproj2_kernel(const float* __restrict__ h1seq,
                              const float* __restrict__ W_ih1,
                              const float* __restrict__ b_ih1,
                              const float* __restrict__ b_hh1,
                              float* __restrict__ xp2)
{
    const int t = blockIdx.x;
    const int g = threadIdx.x;
    __shared__ f4 sh[H1_ / 4];
    if (g < H1_ / 4) sh[g] = ((const f4*)(h1seq + (size_t)t * H1_))[g];
    __syncthreads();
    const f4* w = (const f4*)(W_ih1 + (size_t)g * H1_);
    float ax = 0.f, ay = 0.f, az = 0.f, aw = 0.f;
#pragma unroll
    for (int k = 0; k < H1_ / 4; ++k) {
        const f4 h4 = sh[k]; const f4 w4 = w[k];
        ax = fmaf(w4.x, h4.x, ax); ay = fmaf(w4.y, h4.y, ay);
        az = fmaf(w4.z, h4.z, az); aw = fmaf(w4.w, h4.w, aw);
    }
    xp2[(size_t)t * G2_ + g] = ((ax + ay) + (az + aw)) + b_ih1[g] + b_hh1[g];
}

// ---------------- B2: layer-2 scan (serial, one block) -----------------------
// 256 threads (4 waves). Thread g owns the FULL W_hh1 row (16 f4, asm-loaded).
// No partial combine: sg2[g] is the complete recurrent dot. 2 barriers/step.
__global__ __attribute__((amdgpu_flat_work_group_size(256, 256),
                          amdgpu_waves_per_eu(1, 1)))
void lstm2_kernel(const float* __restrict__ xp2,
                  const float* __restrict__ W_hh1,
                  float* __restrict__ h2seq)
{
    const int tid = threadIdx.x;       // gate index 0..255

    __shared__ f4    sh2[H2_ / 4];     // h2 state (64 f32)
    __shared__ float sg2[G2_];         // full gate pre-activations

    const f4* pw = (const f4*)(W_hh1 + (size_t)tid * H2_);
    f4 w_0, w_1, w_2, w_3, w_4, w_5, w_6, w_7,
       w_8, w_9, w_10, w_11, w_12, w_13, w_14, w_15;
    ASM_LOAD_16Q(pw);

    if (tid < H2_ / 4) sh2[tid] = f4{0.f, 0.f, 0.f, 0.f};
    float c2 = 0.0f;                   // owned by tid < 64
    __syncthreads();

    float xp_cur = xp2[tid];

    for (int t = 0; t < T_STEPS; ++t) {
        float xp_next;
        {
            const int tn = (t + 1 < T_STEPS) ? (t + 1) : (T_STEPS - 1);
            xp_next = xp2[(size_t)tn * G2_ + tid];
        }

        float ax = 0.f, ay = 0.f, az = 0.f, aw = 0.f;
#define P1S(k) { const f4 h4 = sh2[k];                                       \
        ax = fmaf(w_##k.x, h4.x, ax); ay = fmaf(w_##k.y, h4.y, ay);          \
        az = fmaf(w_##k.z, h4.z, az); aw = fmaf(w_##k.w, h4.w, aw); }
        REP16(P1S)
#undef P1S
        sg2[tid] = ((ax + ay) + (az + aw)) + xp_cur;
        __syncthreads();   // sg2 ready (also orders prev h2 writes)

        if (tid < H2_) {
            const float vi = sg2[tid];
            const float vf = sg2[H2_ + tid];
            const float vg = sg2[2 * H2_ + tid];
            const float vo = sg2[3 * H2_ + tid];
            c2 = fmaf(sigmoidf_(vf), c2, sigmoidf_(vi) * tanhf_(vg));
            const float h = sigmoidf_(vo) * tanhf_(c2);
            ((float*)sh2)[tid] = h;
            h2seq[(size_t)t * H2_ + tid] = h;
        }
        __syncthreads();   // h2_new ready
        xp_cur = xp_next;
    }
}

// ---------------- D: head out[t,o] = relu(h2[t]) . W_d[o] + b_d --------------
__global__ void head_kernel(const float* __restrict__ h2seq,
                            const float* __restrict__ W_d,
                            const float* __restrict__ b_d,
                            float* __restrict__ out)
{
    const int idx = blockIdx.x * blockDim.x + threadIdx.x;
    if (idx >= T_STEPS * OUT_F) return;
    const int t = idx / OUT_F;
    const int o = idx - t * OUT_F;
    const float* hr = h2seq + (size_t)t * H2_;
    const float* w  = W_d + o * H2_;
    float acc = b_d[o];
#pragma unroll
    for (int j = 0; j < H2_; ++j) acc = fmaf(fmaxf(hr[j], 0.0f), w[j], acc);
    out[idx] = acc;
}

extern "C" void kernel_launch(void* const* d_in, const int* in_sizes, int n_in,
                              void* d_out, int out_size, void* d_ws, size_t ws_size,
                              hipStream_t stream) {
    const float* x     = (const float*)d_in[0];
    const float* W_ih0 = (const float*)d_in[1];
    const float* W_hh0 = (const float*)d_in[2];
    const float* b_ih0 = (const float*)d_in[3];
    const float* b_hh0 = (const float*)d_in[4];
    const float* W_ih1 = (const float*)d_in[5];
    const float* W_hh1 = (const float*)d_in[6];
    const float* b_ih1 = (const float*)d_in[7];
    const float* b_hh1 = (const float*)d_in[8];
    const float* W_d   = (const float*)d_in[9];
    const float* b_d   = (const float*)d_in[10];

    float* out   = (float*)d_out;
    float* xp1   = (float*)d_ws;                       // [1024][512] = 2 MB
    float* h1seq = xp1 + (size_t)T_STEPS * G1_;        // [1024][128] = 512 KB
    float* h2seq = h1seq + (size_t)T_STEPS * H1_;      // [1024][64]  = 256 KB
    float* xp2   = xp1;                                // overlay (xp1 dead after B1)

    hipLaunchKernelGGL(xproj_kernel, dim3(T_STEPS), dim3(G1_), 0, stream,
                       x, W_ih0, b_ih0, b_hh0, xp1);
    hipLaunchKernelGGL(lstm1_kernel, dim3(1), dim3(1024), 0, stream,
                       xp1, W_hh0, h1seq);
    hipLaunchKernelGGL(xproj2_kernel, dim3(T_STEPS), dim3(G2_), 0, stream,
                       h1seq, W_ih1, b_ih1, b_hh1, xp2);
    hipLaunchKernelGGL(lstm2_kernel, dim3(1), dim3(512 / 2), 0, stream,
                       xp2, W_hh1, h2seq);
    hipLaunchKernelGGL(head_kernel, dim3((T_STEPS * OUT_F + 255) / 256), dim3(256),
                       0, stream, h2seq, W_d, b_d, out);
}